// Round 3
// baseline (42.822 us; speedup 1.0000x reference)
//
#include <hip/hip_runtime.h>

#define IMG_H 512
#define IMG_W 512
#define MAX_STREAKS 64

typedef float v4f __attribute__((ext_vector_type(4)));

// Kernel 1: rasterize overlap count K[h][w] and store f = (1-a)^K into ws.
__global__ void __launch_bounds__(256)
rain_factor_kernel(const float* __restrict__ alpha,
                   const int* __restrict__ xc,
                   const int* __restrict__ y0,
                   const int* __restrict__ y1_off,
                   float* __restrict__ f,
                   int n_streaks) {
    __shared__ int s_xc[MAX_STREAKS], s_y0[MAX_STREAKS], s_y1[MAX_STREAKS];
    int tid = threadIdx.x;
    if (tid < n_streaks) {
        s_xc[tid] = xc[tid];
        s_y0[tid] = y0[tid];
        s_y1[tid] = y1_off[tid] + IMG_H / 2;
    }
    __syncthreads();

    float l2f = __log2f(1.0f - alpha[0]);

    int idx = blockIdx.x * blockDim.x + threadIdx.x;
    if (idx >= IMG_H * IMG_W) return;
    int h = idx >> 9;        // / IMG_W
    int w = idx & (IMG_W - 1);

    int k = 0;
    #pragma unroll 8
    for (int s = 0; s < n_streaks; ++s) {
        int c  = s_xc[s];
        int c0 = c - 1 > 0 ? c - 1 : 0;
        int hit = (h >= s_y0[s]) & (h < s_y1[s]) & (w >= c0) & (w < c + 1);
        k += hit;
    }
    // (1-a)^k; k==0 -> exp2(0) == 1.0 exactly
    f[idx] = exp2f(l2f * (float)k);
}

__device__ __forceinline__ v4f blend4(v4f xv, v4f fv) {
    v4f o;
    o.x = fminf(fmaxf(fmaf(xv.x, fv.x, 1.0f - fv.x), 0.0f), 1.0f);
    o.y = fminf(fmaxf(fmaf(xv.y, fv.y, 1.0f - fv.y), 0.0f), 1.0f);
    o.z = fminf(fmaxf(fmaf(xv.z, fv.z, 1.0f - fv.z), 0.0f), 1.0f);
    o.w = fminf(fmaxf(fmaf(xv.w, fv.w, 1.0f - fv.w), 0.0f), 1.0f);
    return o;
}

// Kernel 2: out = clip(x*f + (1-f), 0, 1).
// 4 independent float4s per thread (ILP), nontemporal x/out (streaming),
// f stays cache-resident (1 MiB).
__global__ void __launch_bounds__(256)
rain_apply_kernel(const v4f* __restrict__ x,
                  const v4f* __restrict__ f,
                  v4f* __restrict__ out,
                  int n4) {
    const int fmask = (IMG_H * IMG_W / 4) - 1;  // 65535
    const int nthreads = gridDim.x * blockDim.x;
    const int base = blockIdx.x * blockDim.x + threadIdx.x;

    int i0 = base;
    int i1 = base + nthreads;
    int i2 = base + 2 * nthreads;
    int i3 = base + 3 * nthreads;

    v4f x0, x1, x2, x3, f0, f1, f2, f3;
    bool v0 = i0 < n4, v1 = i1 < n4, v2 = i2 < n4, v3 = i3 < n4;
    if (v0) { x0 = __builtin_nontemporal_load(&x[i0]); f0 = f[i0 & fmask]; }
    if (v1) { x1 = __builtin_nontemporal_load(&x[i1]); f1 = f[i1 & fmask]; }
    if (v2) { x2 = __builtin_nontemporal_load(&x[i2]); f2 = f[i2 & fmask]; }
    if (v3) { x3 = __builtin_nontemporal_load(&x[i3]); f3 = f[i3 & fmask]; }

    if (v0) __builtin_nontemporal_store(blend4(x0, f0), &out[i0]);
    if (v1) __builtin_nontemporal_store(blend4(x1, f1), &out[i1]);
    if (v2) __builtin_nontemporal_store(blend4(x2, f2), &out[i2]);
    if (v3) __builtin_nontemporal_store(blend4(x3, f3), &out[i3]);
}

extern "C" void kernel_launch(void* const* d_in, const int* in_sizes, int n_in,
                              void* d_out, int out_size, void* d_ws, size_t ws_size,
                              hipStream_t stream) {
    const float* x      = (const float*)d_in[0];
    const float* alpha  = (const float*)d_in[1];
    const int*   xc     = (const int*)d_in[2];
    const int*   y0     = (const int*)d_in[3];
    const int*   y1_off = (const int*)d_in[4];
    float* out = (float*)d_out;
    float* f   = (float*)d_ws;   // needs IMG_H*IMG_W*4 = 1 MiB

    int n_streaks = in_sizes[2];

    // Kernel 1: 512*512 pixels
    {
        int threads = 256;
        int blocks = (IMG_H * IMG_W + threads - 1) / threads;  // 1024
        rain_factor_kernel<<<blocks, threads, 0, stream>>>(alpha, xc, y0, y1_off, f, n_streaks);
    }

    // Kernel 2: elementwise blend, 4 float4 per thread
    {
        int n4 = out_size / 4;                       // 6,291,456
        int threads = 256;
        int elems_per_block = threads * 4;           // 1024 float4
        int blocks = (n4 + elems_per_block - 1) / elems_per_block;  // 6144
        rain_apply_kernel<<<blocks, threads, 0, stream>>>(
            (const v4f*)x, (const v4f*)f, (v4f*)out, n4);
    }
}

// Round 4
// 38.701 us; speedup vs baseline: 1.1065x; 1.1065x over previous
//
#include <hip/hip_runtime.h>

#define IMG_H 512
#define IMG_W 512
#define MAX_STREAKS 64

typedef float v4f __attribute__((ext_vector_type(4)));

// Kernel 1: rasterize overlap count K[h][w] and store f = (1-a)^K into ws.
__global__ void __launch_bounds__(256)
rain_factor_kernel(const float* __restrict__ alpha,
                   const int* __restrict__ xc,
                   const int* __restrict__ y0,
                   const int* __restrict__ y1_off,
                   float* __restrict__ f,
                   int n_streaks) {
    __shared__ int s_xc[MAX_STREAKS], s_y0[MAX_STREAKS], s_y1[MAX_STREAKS];
    int tid = threadIdx.x;
    if (tid < n_streaks) {
        s_xc[tid] = xc[tid];
        s_y0[tid] = y0[tid];
        s_y1[tid] = y1_off[tid] + IMG_H / 2;
    }
    __syncthreads();

    float l2f = __log2f(1.0f - alpha[0]);

    int idx = blockIdx.x * blockDim.x + threadIdx.x;
    if (idx >= IMG_H * IMG_W) return;
    int h = idx >> 9;        // / IMG_W
    int w = idx & (IMG_W - 1);

    int k = 0;
    #pragma unroll 8
    for (int s = 0; s < n_streaks; ++s) {
        int c  = s_xc[s];
        int c0 = c - 1 > 0 ? c - 1 : 0;
        int hit = (h >= s_y0[s]) & (h < s_y1[s]) & (w >= c0) & (w < c + 1);
        k += hit;
    }
    // (1-a)^k; k==0 -> exp2(0) == 1.0 exactly
    f[idx] = exp2f(l2f * (float)k);
}

__device__ __forceinline__ v4f blend4(v4f xv, v4f fv) {
    v4f o;
    o.x = fminf(fmaxf(fmaf(xv.x, fv.x, 1.0f - fv.x), 0.0f), 1.0f);
    o.y = fminf(fmaxf(fmaf(xv.y, fv.y, 1.0f - fv.y), 0.0f), 1.0f);
    o.z = fminf(fmaxf(fmaf(xv.z, fv.z, 1.0f - fv.z), 0.0f), 1.0f);
    o.w = fminf(fmaxf(fmaf(xv.w, fv.w, 1.0f - fv.w), 0.0f), 1.0f);
    return o;
}

// Kernel 2: out = clip(x*f + (1-f), 0, 1).
// Cached loads for x/f (x rides the 256MB L3 across replays, f is 1MB);
// nontemporal stores for out (write-only — don't evict x from L3).
// 4 independent float4s per thread for MLP-level ILP.
__global__ void __launch_bounds__(256)
rain_apply_kernel(const v4f* __restrict__ x,
                  const v4f* __restrict__ f,
                  v4f* __restrict__ out,
                  int n4) {
    const int fmask = (IMG_H * IMG_W / 4) - 1;  // 65535
    const int nthreads = gridDim.x * blockDim.x;
    const int base = blockIdx.x * blockDim.x + threadIdx.x;

    int i0 = base;
    int i1 = base + nthreads;
    int i2 = base + 2 * nthreads;
    int i3 = base + 3 * nthreads;

    v4f x0, x1, x2, x3, f0, f1, f2, f3;
    bool v0 = i0 < n4, v1 = i1 < n4, v2 = i2 < n4, v3 = i3 < n4;
    if (v0) { x0 = x[i0]; f0 = f[i0 & fmask]; }
    if (v1) { x1 = x[i1]; f1 = f[i1 & fmask]; }
    if (v2) { x2 = x[i2]; f2 = f[i2 & fmask]; }
    if (v3) { x3 = x[i3]; f3 = f[i3 & fmask]; }

    if (v0) __builtin_nontemporal_store(blend4(x0, f0), &out[i0]);
    if (v1) __builtin_nontemporal_store(blend4(x1, f1), &out[i1]);
    if (v2) __builtin_nontemporal_store(blend4(x2, f2), &out[i2]);
    if (v3) __builtin_nontemporal_store(blend4(x3, f3), &out[i3]);
}

extern "C" void kernel_launch(void* const* d_in, const int* in_sizes, int n_in,
                              void* d_out, int out_size, void* d_ws, size_t ws_size,
                              hipStream_t stream) {
    const float* x      = (const float*)d_in[0];
    const float* alpha  = (const float*)d_in[1];
    const int*   xc     = (const int*)d_in[2];
    const int*   y0     = (const int*)d_in[3];
    const int*   y1_off = (const int*)d_in[4];
    float* out = (float*)d_out;
    float* f   = (float*)d_ws;   // needs IMG_H*IMG_W*4 = 1 MiB

    int n_streaks = in_sizes[2];

    // Kernel 1: 512*512 pixels
    {
        int threads = 256;
        int blocks = (IMG_H * IMG_W + threads - 1) / threads;  // 1024
        rain_factor_kernel<<<blocks, threads, 0, stream>>>(alpha, xc, y0, y1_off, f, n_streaks);
    }

    // Kernel 2: elementwise blend, 4 float4 per thread
    {
        int n4 = out_size / 4;                       // 6,291,456
        int threads = 256;
        int elems_per_block = threads * 4;           // 1024 float4
        int blocks = (n4 + elems_per_block - 1) / elems_per_block;  // 6144
        rain_apply_kernel<<<blocks, threads, 0, stream>>>(
            (const v4f*)x, (const v4f*)f, (v4f*)out, n4);
    }
}

// Round 5
// 36.357 us; speedup vs baseline: 1.1778x; 1.0645x over previous
//
#include <hip/hip_runtime.h>

#define IMG_H 512
#define IMG_W 512
#define MAX_STREAKS 64
#define ROWS_PER_BLOCK 8   // 8 rows * 512 cols = 4096 scalars = 1024 float4 per block

typedef float v4f __attribute__((ext_vector_type(4)));

__device__ __forceinline__ v4f blend4(v4f xv, v4f fv) {
    v4f o;
    o.x = fminf(fmaxf(fmaf(xv.x, fv.x, 1.0f - fv.x), 0.0f), 1.0f);
    o.y = fminf(fmaxf(fmaf(xv.y, fv.y, 1.0f - fv.y), 0.0f), 1.0f);
    o.z = fminf(fmaxf(fmaf(xv.z, fv.z, 1.0f - fv.z), 0.0f), 1.0f);
    o.w = fminf(fmaxf(fmaf(xv.w, fv.w, 1.0f - fv.w), 0.0f), 1.0f);
    return o;
}

// Fused: per block, rasterize the streak overlap-count for its 8 image rows
// into LDS (O(streaks) atomics, streaks are <=2 columns wide), convert to
// f=(1-a)^k in place, then stream x -> out with f from LDS.
// Loads of x cached (L3-resident across replays); stores nontemporal
// (write-only, don't evict x from L3).
__global__ void __launch_bounds__(256)
rain_fused_kernel(const v4f* __restrict__ x,
                  const float* __restrict__ alpha,
                  const int* __restrict__ xc,
                  const int* __restrict__ y0,
                  const int* __restrict__ y1_off,
                  v4f* __restrict__ out,
                  int n_streaks) {
    __shared__ int s_xc[MAX_STREAKS], s_y0[MAX_STREAKS], s_y1[MAX_STREAKS];
    __shared__ float s_f[ROWS_PER_BLOCK][IMG_W];        // 16 KB; int during build
    int* s_hist = (int*)&s_f[0][0];

    const int tid = threadIdx.x;
    if (tid < n_streaks) {
        s_xc[tid] = xc[tid];
        s_y0[tid] = y0[tid];
        s_y1[tid] = y1_off[tid] + IMG_H / 2;
    }
    #pragma unroll
    for (int i = tid; i < ROWS_PER_BLOCK * IMG_W; i += 256) s_hist[i] = 0;
    __syncthreads();

    // Which 8 rows of the 512x512 image does this block cover?
    const int hbase = (blockIdx.x * ROWS_PER_BLOCK) & (IMG_H - 1);

    // Rasterize: one (row, streak) pair per work item; each streak adds +1 to
    // at most 2 columns of that row.
    for (int p = tid; p < (n_streaks << 3); p += 256) {
        int r = p & 7, s = p >> 3;
        int h = hbase + r;
        if (h >= s_y0[s] && h < s_y1[s]) {
            int c = s_xc[s];
            atomicAdd(&s_hist[(r << 9) + (c - 1 > 0 ? c - 1 : 0)], 1);
            if (c >= 1) atomicAdd(&s_hist[(r << 9) + c], 1);
        }
    }
    __syncthreads();

    // Convert count -> factor in place (each slot owned by one thread).
    const float l2f = __log2f(1.0f - alpha[0]);
    #pragma unroll
    for (int i = tid; i < ROWS_PER_BLOCK * IMG_W; i += 256) {
        int k = s_hist[i];
        ((float*)s_hist)[i] = exp2f(l2f * (float)k);   // k==0 -> exactly 1.0f
    }
    __syncthreads();

    // Stream: 4 independent float4 per thread, block-contiguous.
    const v4f* xb = x + (size_t)blockIdx.x * 1024;
    v4f*       ob = out + (size_t)blockIdx.x * 1024;
    const v4f* fb = (const v4f*)&s_f[0][0];
    #pragma unroll
    for (int k = 0; k < 4; ++k) {
        int idx = (k << 8) + tid;           // [0, 1024)
        v4f xv = xb[idx];
        v4f fv = fb[idx];                   // ds_read_b128, per-lane 16B
        __builtin_nontemporal_store(blend4(xv, fv), &ob[idx]);
    }
}

extern "C" void kernel_launch(void* const* d_in, const int* in_sizes, int n_in,
                              void* d_out, int out_size, void* d_ws, size_t ws_size,
                              hipStream_t stream) {
    const float* x      = (const float*)d_in[0];
    const float* alpha  = (const float*)d_in[1];
    const int*   xc     = (const int*)d_in[2];
    const int*   y0     = (const int*)d_in[3];
    const int*   y1_off = (const int*)d_in[4];
    float* out = (float*)d_out;

    int n_streaks = in_sizes[2];

    // out_size = 32*3*512*512 = 25,165,824 scalars; 4096 per block -> 6144 blocks exactly.
    int blocks = out_size / (ROWS_PER_BLOCK * IMG_W);
    rain_fused_kernel<<<blocks, 256, 0, stream>>>(
        (const v4f*)x, alpha, xc, y0, y1_off, (v4f*)out, n_streaks);
}